// Round 1
// baseline (795.078 us; speedup 1.0000x reference)
//
#include <hip/hip_runtime.h>

#define NN   65536
#define NE   1048576
#define FIN  128
#define HD   64
#define NOUT 32
#define EPSV 1e-5f

__device__ __forceinline__ float wsum(float v) {
#pragma unroll
  for (int o = 32; o > 0; o >>= 1) v += __shfl_xor(v, o, 64);
  return v;
}

// ---------------- CSR build (dst-sorted) ----------------

__global__ void hist_k(const int* __restrict__ dst, int* counts) {
  int i = blockIdx.x * blockDim.x + threadIdx.x;
  atomicAdd(&counts[dst[i]], 1);
}

// 1 block, 1024 threads; each thread owns 64 consecutive counts.
// Writes exclusive-prefix into rowptr AND into counts_cursor (reused as cursor).
__global__ __launch_bounds__(1024) void scan_k(int* counts_cursor, int* rowptr) {
  __shared__ int ss[1024];
  int t = threadIdx.x;
  int base = t * 64;
  int s = 0;
  for (int i = 0; i < 64; ++i) s += counts_cursor[base + i];
  ss[t] = s;
  __syncthreads();
  for (int off = 1; off < 1024; off <<= 1) {
    int v = (t >= off) ? ss[t - off] : 0;
    __syncthreads();
    ss[t] += v;
    __syncthreads();
  }
  int prefix = (t == 0) ? 0 : ss[t - 1];  // exclusive over thread chunks
  for (int i = 0; i < 64; ++i) {
    int c = counts_cursor[base + i];      // read original count
    rowptr[base + i] = prefix;
    counts_cursor[base + i] = prefix;     // becomes scatter cursor
    prefix += c;
  }
  if (t == 1023) rowptr[NN] = prefix;     // == NE
}

__global__ void scatter_k(const int* __restrict__ src, const int* __restrict__ dst,
                          const float* __restrict__ ew, int* cursor,
                          int* s_src, float* s_w) {
  int i = blockIdx.x * blockDim.x + threadIdx.x;
  int d = dst[i];
  int pos = atomicAdd(&cursor[d], 1);
  s_src[pos] = src[i];
  s_w[pos] = ew[i];
}

// ---------------- fc_first: LN(128) -> [128x64] -> ELU -> LN(64) ----------------
// 256 threads = 4 waves = 4 nodes/block. w1 (32KB) staged in LDS.
__global__ __launch_bounds__(256) void fc_first_k(
    const float* __restrict__ x, const float* __restrict__ ln1_g,
    const float* __restrict__ ln1_b, const float* __restrict__ w1,
    const float* __restrict__ b1, const float* __restrict__ ln_g,
    const float* __restrict__ ln_b, float* __restrict__ hA) {
  __shared__ float sW[FIN * HD];   // 32 KB
  __shared__ float sx[4][FIN];
  int tid = threadIdx.x;
  for (int i = tid; i < FIN * HD; i += 256) sW[i] = w1[i];
  int wl = tid >> 6, lane = tid & 63;
  int node = blockIdx.x * 4 + wl;

  float x0 = x[(size_t)node * FIN + lane];
  float x1 = x[(size_t)node * FIN + 64 + lane];
  float mean = wsum(x0 + x1) * (1.f / FIN);
  float d0 = x0 - mean, d1 = x1 - mean;
  float var = wsum(d0 * d0 + d1 * d1) * (1.f / FIN);
  float r = rsqrtf(var + EPSV);
  sx[wl][lane]      = d0 * r * ln1_g[lane]      + ln1_b[lane];
  sx[wl][64 + lane] = d1 * r * ln1_g[64 + lane] + ln1_b[64 + lane];
  __syncthreads();

  float y = b1[lane];
#pragma unroll 8
  for (int k = 0; k < FIN; ++k) y += sx[wl][k] * sW[k * HD + lane];
  y = (y > 0.f) ? y : expm1f(y);   // ELU

  float m2 = wsum(y) * (1.f / HD);
  float d = y - m2;
  float v2 = wsum(d * d) * (1.f / HD);
  float h = d * rsqrtf(v2 + EPSV) * ln_g[lane] + ln_b[lane];
  hA[(size_t)node * HD + lane] = h;
}

// ---------------- conv layer: gather-agg -> [64x64]+b -> LN -> h += ----------------
__global__ __launch_bounds__(256) void conv_k(
    const float* __restrict__ h_in, float* __restrict__ h_out,
    const int* __restrict__ rowptr, const int* __restrict__ e_src,
    const float* __restrict__ e_w, const float* __restrict__ W,
    const float* __restrict__ B, const float* __restrict__ ln_g,
    const float* __restrict__ ln_b) {
  __shared__ float sW[HD * HD];    // 16 KB
  __shared__ float sagg[4][HD];
  int tid = threadIdx.x;
  for (int i = tid; i < HD * HD; i += 256) sW[i] = W[i];
  int wl = tid >> 6, lane = tid & 63;
  int n = blockIdx.x * 4 + wl;

  int beg = rowptr[n], end = rowptr[n + 1];
  float acc = 0.f;
  for (int e = beg; e < end; ++e) {
    int s = e_src[e];
    float w = e_w[e];
    acc += h_in[(size_t)s * HD + lane] * w;
  }
  sagg[wl][lane] = acc;
  __syncthreads();

  float y = B[lane];
#pragma unroll 8
  for (int k = 0; k < HD; ++k) y += sagg[wl][k] * sW[k * HD + lane];

  float m = wsum(y) * (1.f / HD);
  float d = y - m;
  float v = wsum(d * d) * (1.f / HD);
  float ln = d * rsqrtf(v + EPSV) * ln_g[lane] + ln_b[lane];
  h_out[(size_t)n * HD + lane] = h_in[(size_t)n * HD + lane] + ln;
}

// ---------------- fc_final: LN(64) -> [64x64]+b -> ELU -> [64x32]+b ----------------
__global__ __launch_bounds__(256) void fc_final_k(
    const float* __restrict__ h, const float* __restrict__ ln2_g,
    const float* __restrict__ ln2_b, const float* __restrict__ w3,
    const float* __restrict__ b3, const float* __restrict__ w4,
    const float* __restrict__ b4, float* __restrict__ out) {
  __shared__ float sW3[HD * HD];     // 16 KB
  __shared__ float sW4[HD * NOUT];   // 8 KB
  __shared__ float sx[4][HD];
  __shared__ float sz[4][HD];
  int tid = threadIdx.x;
  for (int i = tid; i < HD * HD; i += 256) sW3[i] = w3[i];
  for (int i = tid; i < HD * NOUT; i += 256) sW4[i] = w4[i];
  int wl = tid >> 6, lane = tid & 63;
  int n = blockIdx.x * 4 + wl;

  float hv = h[(size_t)n * HD + lane];
  float m = wsum(hv) * (1.f / HD);
  float d = hv - m;
  float v = wsum(d * d) * (1.f / HD);
  sx[wl][lane] = d * rsqrtf(v + EPSV) * ln2_g[lane] + ln2_b[lane];
  __syncthreads();

  float y = b3[lane];
#pragma unroll 8
  for (int k = 0; k < HD; ++k) y += sx[wl][k] * sW3[k * HD + lane];
  y = (y > 0.f) ? y : expm1f(y);
  sz[wl][lane] = y;
  __syncthreads();

  if (lane < NOUT) {
    float o = b4[lane];
#pragma unroll 8
    for (int j = 0; j < HD; ++j) o += sz[wl][j] * sW4[j * NOUT + lane];
    out[(size_t)n * NOUT + lane] = o;
  }
}

extern "C" void kernel_launch(void* const* d_in, const int* in_sizes, int n_in,
                              void* d_out, int out_size, void* d_ws, size_t ws_size,
                              hipStream_t stream) {
  const float* x      = (const float*)d_in[0];
  const float* ew     = (const float*)d_in[1];
  const int*   src    = (const int*)d_in[2];
  const int*   dst    = (const int*)d_in[3];
  const float* ln1_g  = (const float*)d_in[4];
  const float* ln1_b  = (const float*)d_in[5];
  const float* w1     = (const float*)d_in[6];
  const float* b1     = (const float*)d_in[7];
  const float* ln_g   = (const float*)d_in[8];
  const float* ln_b   = (const float*)d_in[9];
  const float* conv_w = (const float*)d_in[10];
  const float* conv_b = (const float*)d_in[11];
  const float* ln2_g  = (const float*)d_in[12];
  const float* ln2_b  = (const float*)d_in[13];
  const float* w3     = (const float*)d_in[14];
  const float* b3     = (const float*)d_in[15];
  const float* w4     = (const float*)d_in[16];
  const float* b4     = (const float*)d_in[17];
  float* out = (float*)d_out;

  char* ws = (char*)d_ws;
  float* hA     = (float*)ws;                       // N*64 f32 = 16 MB
  float* hB     = hA + (size_t)NN * HD;             // 16 MB
  int*   rowptr = (int*)(hB + (size_t)NN * HD);     // N+1 (padded)
  int*   cursor = rowptr + (NN + 64);               // N (counts, then cursor)
  int*   s_src  = cursor + NN;                      // E
  float* s_w    = (float*)(s_src + NE);             // E

  hipMemsetAsync(cursor, 0, NN * sizeof(int), stream);
  hist_k<<<NE / 256, 256, 0, stream>>>(dst, cursor);
  scan_k<<<1, 1024, 0, stream>>>(cursor, rowptr);
  scatter_k<<<NE / 256, 256, 0, stream>>>(src, dst, ew, cursor, s_src, s_w);

  fc_first_k<<<NN / 4, 256, 0, stream>>>(x, ln1_g, ln1_b, w1, b1, ln_g, ln_b, hA);
  conv_k<<<NN / 4, 256, 0, stream>>>(hA, hB, rowptr, s_src, s_w,
                                     conv_w,        conv_b,       ln_g, ln_b);
  conv_k<<<NN / 4, 256, 0, stream>>>(hB, hA, rowptr, s_src, s_w,
                                     conv_w + 4096, conv_b + 64,  ln_g, ln_b);
  conv_k<<<NN / 4, 256, 0, stream>>>(hA, hB, rowptr, s_src, s_w,
                                     conv_w + 8192, conv_b + 128, ln_g, ln_b);
  fc_final_k<<<NN / 4, 256, 0, stream>>>(hB, ln2_g, ln2_b, w3, b3, w4, b4, out);
}

// Round 2
// 602.728 us; speedup vs baseline: 1.3191x; 1.3191x over previous
//
#include <hip/hip_runtime.h>

#define NN   65536
#define NE   1048576
#define FIN  128
#define HD   64
#define NOUT 32
#define EPSV 1e-5f

__device__ __forceinline__ float wsum(float v) {
#pragma unroll
  for (int o = 32; o > 0; o >>= 1) v += __shfl_xor(v, o, 64);
  return v;
}

// ---------------- CSR build (dst-sorted, packed edges) ----------------

__global__ void hist_k(const int* __restrict__ dst, int* counts) {
  int i = blockIdx.x * blockDim.x + threadIdx.x;
  atomicAdd(&counts[dst[i]], 1);
}

// 1 block, 1024 threads; each thread owns 64 consecutive counts.
__global__ __launch_bounds__(1024) void scan_k(int* counts_cursor, int* rowptr) {
  __shared__ int ss[1024];
  int t = threadIdx.x;
  int base = t * 64;
  int s = 0;
  for (int i = 0; i < 64; ++i) s += counts_cursor[base + i];
  ss[t] = s;
  __syncthreads();
  for (int off = 1; off < 1024; off <<= 1) {
    int v = (t >= off) ? ss[t - off] : 0;
    __syncthreads();
    ss[t] += v;
    __syncthreads();
  }
  int prefix = (t == 0) ? 0 : ss[t - 1];
  for (int i = 0; i < 64; ++i) {
    int c = counts_cursor[base + i];
    rowptr[base + i] = prefix;
    counts_cursor[base + i] = prefix;
    prefix += c;
  }
  if (t == 1023) rowptr[NN] = prefix;
}

__global__ void scatter_k(const int* __restrict__ src, const int* __restrict__ dst,
                          const float* __restrict__ ew, int* cursor,
                          int2* __restrict__ edge) {
  int i = blockIdx.x * blockDim.x + threadIdx.x;
  int d = dst[i];
  int pos = atomicAdd(&cursor[d], 1);
  edge[pos] = make_int2(src[i], __float_as_int(ew[i]));
}

// ---------------- fc_first: LN(128) -> [128x64] -> ELU -> LN(64) ----------------
// 512 threads = 8 waves = 8 nodes/block.
__global__ __launch_bounds__(512) void fc_first_k(
    const float* __restrict__ x, const float* __restrict__ ln1_g,
    const float* __restrict__ ln1_b, const float* __restrict__ w1,
    const float* __restrict__ b1, const float* __restrict__ ln_g,
    const float* __restrict__ ln_b, float* __restrict__ hA) {
  __shared__ float sW[FIN * HD];   // 32 KB
  __shared__ float sx[8][FIN];     // 4 KB
  int tid = threadIdx.x;
  for (int i = tid; i < FIN * HD; i += 512) sW[i] = w1[i];
  int wl = tid >> 6, lane = tid & 63;
  int node = blockIdx.x * 8 + wl;

  float x0 = x[(size_t)node * FIN + lane];
  float x1 = x[(size_t)node * FIN + 64 + lane];
  float mean = wsum(x0 + x1) * (1.f / FIN);
  float d0 = x0 - mean, d1 = x1 - mean;
  float var = wsum(d0 * d0 + d1 * d1) * (1.f / FIN);
  float r = rsqrtf(var + EPSV);
  sx[wl][lane]      = d0 * r * ln1_g[lane]      + ln1_b[lane];
  sx[wl][64 + lane] = d1 * r * ln1_g[64 + lane] + ln1_b[64 + lane];
  __syncthreads();

  float y = b1[lane];
#pragma unroll 8
  for (int k = 0; k < FIN; ++k) y += sx[wl][k] * sW[k * HD + lane];
  y = (y > 0.f) ? y : expm1f(y);   // ELU

  float m2 = wsum(y) * (1.f / HD);
  float d = y - m2;
  float v2 = wsum(d * d) * (1.f / HD);
  float h = d * rsqrtf(v2 + EPSV) * ln_g[lane] + ln_b[lane];
  hA[(size_t)node * HD + lane] = h;
}

// ---------------- conv layer: gather-agg -> [64x64]+b -> LN -> h += ----------------
__global__ __launch_bounds__(512) void conv_k(
    const float* __restrict__ h_in, float* __restrict__ h_out,
    const int* __restrict__ rowptr, const int2* __restrict__ edge,
    const float* __restrict__ W, const float* __restrict__ B,
    const float* __restrict__ ln_g, const float* __restrict__ ln_b) {
  __shared__ float sW[HD * HD];    // 16 KB
  __shared__ float sagg[8][HD];    // 2 KB
  int tid = threadIdx.x;
  for (int i = tid; i < HD * HD; i += 512) sW[i] = W[i];
  int wl = tid >> 6, lane = tid & 63;
  int n = blockIdx.x * 8 + wl;

  int beg = rowptr[n], end = rowptr[n + 1];
  float acc = 0.f;
  int e = beg;
  // 4 independent gathers in flight per iteration
  for (; e + 4 <= end; e += 4) {
    int2 e0 = edge[e], e1 = edge[e + 1], e2 = edge[e + 2], e3 = edge[e + 3];
    float g0 = h_in[(size_t)e0.x * HD + lane];
    float g1 = h_in[(size_t)e1.x * HD + lane];
    float g2 = h_in[(size_t)e2.x * HD + lane];
    float g3 = h_in[(size_t)e3.x * HD + lane];
    acc += g0 * __int_as_float(e0.y);
    acc += g1 * __int_as_float(e1.y);
    acc += g2 * __int_as_float(e2.y);
    acc += g3 * __int_as_float(e3.y);
  }
  for (; e < end; ++e) {
    int2 e0 = edge[e];
    acc += h_in[(size_t)e0.x * HD + lane] * __int_as_float(e0.y);
  }
  sagg[wl][lane] = acc;
  __syncthreads();

  float y = B[lane];
#pragma unroll 8
  for (int k = 0; k < HD; ++k) y += sagg[wl][k] * sW[k * HD + lane];

  float m = wsum(y) * (1.f / HD);
  float d = y - m;
  float v = wsum(d * d) * (1.f / HD);
  float ln = d * rsqrtf(v + EPSV) * ln_g[lane] + ln_b[lane];
  h_out[(size_t)n * HD + lane] = h_in[(size_t)n * HD + lane] + ln;
}

// ---------------- fc_final: LN(64) -> [64x64]+b -> ELU -> [64x32]+b ----------------
__global__ __launch_bounds__(512) void fc_final_k(
    const float* __restrict__ h, const float* __restrict__ ln2_g,
    const float* __restrict__ ln2_b, const float* __restrict__ w3,
    const float* __restrict__ b3, const float* __restrict__ w4,
    const float* __restrict__ b4, float* __restrict__ out) {
  __shared__ float sW3[HD * HD];     // 16 KB
  __shared__ float sW4[HD * NOUT];   // 8 KB
  __shared__ float sx[8][HD];
  __shared__ float sz[8][HD];
  int tid = threadIdx.x;
  for (int i = tid; i < HD * HD; i += 512) sW3[i] = w3[i];
  for (int i = tid; i < HD * NOUT; i += 512) sW4[i] = w4[i];
  int wl = tid >> 6, lane = tid & 63;
  int n = blockIdx.x * 8 + wl;

  float hv = h[(size_t)n * HD + lane];
  float m = wsum(hv) * (1.f / HD);
  float d = hv - m;
  float v = wsum(d * d) * (1.f / HD);
  sx[wl][lane] = d * rsqrtf(v + EPSV) * ln2_g[lane] + ln2_b[lane];
  __syncthreads();

  float y = b3[lane];
#pragma unroll 8
  for (int k = 0; k < HD; ++k) y += sx[wl][k] * sW3[k * HD + lane];
  y = (y > 0.f) ? y : expm1f(y);
  sz[wl][lane] = y;
  __syncthreads();

  if (lane < NOUT) {
    float o = b4[lane];
#pragma unroll 8
    for (int j = 0; j < HD; ++j) o += sz[wl][j] * sW4[j * NOUT + lane];
    out[(size_t)n * NOUT + lane] = o;
  }
}

extern "C" void kernel_launch(void* const* d_in, const int* in_sizes, int n_in,
                              void* d_out, int out_size, void* d_ws, size_t ws_size,
                              hipStream_t stream) {
  const float* x      = (const float*)d_in[0];
  const float* ew     = (const float*)d_in[1];
  const int*   src    = (const int*)d_in[2];
  const int*   dst    = (const int*)d_in[3];
  const float* ln1_g  = (const float*)d_in[4];
  const float* ln1_b  = (const float*)d_in[5];
  const float* w1     = (const float*)d_in[6];
  const float* b1     = (const float*)d_in[7];
  const float* ln_g   = (const float*)d_in[8];
  const float* ln_b   = (const float*)d_in[9];
  const float* conv_w = (const float*)d_in[10];
  const float* conv_b = (const float*)d_in[11];
  const float* ln2_g  = (const float*)d_in[12];
  const float* ln2_b  = (const float*)d_in[13];
  const float* w3     = (const float*)d_in[14];
  const float* b3     = (const float*)d_in[15];
  const float* w4     = (const float*)d_in[16];
  const float* b4     = (const float*)d_in[17];
  float* out = (float*)d_out;

  char* ws = (char*)d_ws;
  float* hA     = (float*)ws;                       // 16 MB
  float* hB     = hA + (size_t)NN * HD;             // 16 MB
  int*   rowptr = (int*)(hB + (size_t)NN * HD);     // N+1 (padded to N+64)
  int*   cursor = rowptr + (NN + 64);               // N
  int2*  edge   = (int2*)(cursor + NN);             // E * 8B

  hipMemsetAsync(cursor, 0, NN * sizeof(int), stream);
  hist_k<<<NE / 256, 256, 0, stream>>>(dst, cursor);
  scan_k<<<1, 1024, 0, stream>>>(cursor, rowptr);
  scatter_k<<<NE / 256, 256, 0, stream>>>(src, dst, ew, cursor, edge);

  fc_first_k<<<NN / 8, 512, 0, stream>>>(x, ln1_g, ln1_b, w1, b1, ln_g, ln_b, hA);
  conv_k<<<NN / 8, 512, 0, stream>>>(hA, hB, rowptr, edge,
                                     conv_w,        conv_b,       ln_g, ln_b);
  conv_k<<<NN / 8, 512, 0, stream>>>(hB, hA, rowptr, edge,
                                     conv_w + 4096, conv_b + 64,  ln_g, ln_b);
  conv_k<<<NN / 8, 512, 0, stream>>>(hA, hB, rowptr, edge,
                                     conv_w + 8192, conv_b + 128, ln_g, ln_b);
  fc_final_k<<<NN / 8, 512, 0, stream>>>(hB, ln2_g, ln2_b, w3, b3, w4, b4, out);
}

// Round 3
// 469.786 us; speedup vs baseline: 1.6924x; 1.2830x over previous
//
#include <hip/hip_runtime.h>

#define NN   65536
#define NE   1048576
#define FIN  128
#define HD   64
#define NOUT 32
#define EPSV 1e-5f

__device__ __forceinline__ float wsum(float v) {
#pragma unroll
  for (int o = 32; o > 0; o >>= 1) v += __shfl_xor(v, o, 64);
  return v;
}

// ---------------- CSR build (dst-sorted, packed edges) ----------------

__global__ void hist_k(const int* __restrict__ dst, int* counts) {
  int i = blockIdx.x * blockDim.x + threadIdx.x;
  atomicAdd(&counts[dst[i]], 1);
}

// Phase A: per-block (256-wide) sums of counts
__global__ __launch_bounds__(256) void scanA_k(const int* __restrict__ counts,
                                               int* __restrict__ bsum) {
  __shared__ int ss[256];
  int t = threadIdx.x;
  ss[t] = counts[blockIdx.x * 256 + t];
  __syncthreads();
  for (int off = 128; off > 0; off >>= 1) {
    if (t < off) ss[t] += ss[t + off];
    __syncthreads();
  }
  if (t == 0) bsum[blockIdx.x] = ss[0];
}

// Phase B: exclusive scan of the 256 block sums (1 block)
__global__ __launch_bounds__(256) void scanB_k(int* __restrict__ bsum) {
  __shared__ int ss[256];
  int t = threadIdx.x;
  ss[t] = bsum[t];
  __syncthreads();
  for (int off = 1; off < 256; off <<= 1) {
    int v = (t >= off) ? ss[t - off] : 0;
    __syncthreads();
    ss[t] += v;
    __syncthreads();
  }
  bsum[t] = (t == 0) ? 0 : ss[t - 1];
}

// Phase C: per-block local exclusive scan + block offset -> rowptr, cursor
__global__ __launch_bounds__(256) void scanC_k(const int* __restrict__ counts,
                                               const int* __restrict__ bsum,
                                               int* __restrict__ rowptr,
                                               int* __restrict__ cursor) {
  __shared__ int ss[256];
  int t = threadIdx.x;
  int g = blockIdx.x * 256 + t;
  int c = counts[g];
  ss[t] = c;
  __syncthreads();
  for (int off = 1; off < 256; off <<= 1) {
    int v = (t >= off) ? ss[t - off] : 0;
    __syncthreads();
    ss[t] += v;
    __syncthreads();
  }
  int excl = ss[t] - c + bsum[blockIdx.x];
  rowptr[g] = excl;
  cursor[g] = excl;
  if (g == NN - 1) rowptr[NN] = excl + c;
}

__global__ void scatter_k(const int* __restrict__ src, const int* __restrict__ dst,
                          const float* __restrict__ ew, int* cursor,
                          int2* __restrict__ edge) {
  int i = blockIdx.x * blockDim.x + threadIdx.x;
  int d = dst[i];
  int pos = atomicAdd(&cursor[d], 1);
  edge[pos] = make_int2(src[i], __float_as_int(ew[i]));
}

// ---------------- fc_first: LN(128) -> [128x64] -> ELU -> LN(64) ----------------
__global__ __launch_bounds__(512) void fc_first_k(
    const float* __restrict__ x, const float* __restrict__ ln1_g,
    const float* __restrict__ ln1_b, const float* __restrict__ w1,
    const float* __restrict__ b1, const float* __restrict__ ln_g,
    const float* __restrict__ ln_b, float* __restrict__ hA) {
  __shared__ float sW[FIN * HD];   // 32 KB
  __shared__ float sx[8][FIN];     // 4 KB
  int tid = threadIdx.x;
  for (int i = tid; i < FIN * HD; i += 512) sW[i] = w1[i];
  int wl = tid >> 6, lane = tid & 63;
  int node = blockIdx.x * 8 + wl;

  float x0 = x[(size_t)node * FIN + lane];
  float x1 = x[(size_t)node * FIN + 64 + lane];
  float mean = wsum(x0 + x1) * (1.f / FIN);
  float d0 = x0 - mean, d1 = x1 - mean;
  float var = wsum(d0 * d0 + d1 * d1) * (1.f / FIN);
  float r = rsqrtf(var + EPSV);
  sx[wl][lane]      = d0 * r * ln1_g[lane]      + ln1_b[lane];
  sx[wl][64 + lane] = d1 * r * ln1_g[64 + lane] + ln1_b[64 + lane];
  __syncthreads();

  float y = b1[lane];
#pragma unroll 8
  for (int k = 0; k < FIN; ++k) y += sx[wl][k] * sW[k * HD + lane];
  y = (y > 0.f) ? y : expm1f(y);   // ELU

  float m2 = wsum(y) * (1.f / HD);
  float d = y - m2;
  float v2 = wsum(d * d) * (1.f / HD);
  float h = d * rsqrtf(v2 + EPSV) * ln_g[lane] + ln_b[lane];
  hA[(size_t)node * HD + lane] = h;
}

// ---------------- conv layer: gather-agg -> [64x64]+b -> LN -> h += ----------------
__global__ __launch_bounds__(512) void conv_k(
    const float* __restrict__ h_in, float* __restrict__ h_out,
    const int* __restrict__ rowptr, const int2* __restrict__ edge,
    const float* __restrict__ W, const float* __restrict__ B,
    const float* __restrict__ ln_g, const float* __restrict__ ln_b) {
  __shared__ float sW[HD * HD];    // 16 KB
  __shared__ float sagg[8][HD];    // 2 KB
  int tid = threadIdx.x;
  for (int i = tid; i < HD * HD; i += 512) sW[i] = W[i];
  int wl = tid >> 6, lane = tid & 63;
  int n = blockIdx.x * 8 + wl;

  int beg = rowptr[n], end = rowptr[n + 1];
  float acc = 0.f;
  int e = beg;
  // 8 independent gathers in flight
  for (; e + 8 <= end; e += 8) {
    int2 E[8];
#pragma unroll
    for (int j = 0; j < 8; ++j) E[j] = edge[e + j];
    float g[8];
#pragma unroll
    for (int j = 0; j < 8; ++j) g[j] = h_in[(size_t)E[j].x * HD + lane];
#pragma unroll
    for (int j = 0; j < 8; ++j) acc += g[j] * __int_as_float(E[j].y);
  }
  for (; e + 4 <= end; e += 4) {
    int2 E[4];
#pragma unroll
    for (int j = 0; j < 4; ++j) E[j] = edge[e + j];
    float g[4];
#pragma unroll
    for (int j = 0; j < 4; ++j) g[j] = h_in[(size_t)E[j].x * HD + lane];
#pragma unroll
    for (int j = 0; j < 4; ++j) acc += g[j] * __int_as_float(E[j].y);
  }
  for (; e < end; ++e) {
    int2 e0 = edge[e];
    acc += h_in[(size_t)e0.x * HD + lane] * __int_as_float(e0.y);
  }
  sagg[wl][lane] = acc;
  __syncthreads();

  float y = B[lane];
#pragma unroll 8
  for (int k = 0; k < HD; ++k) y += sagg[wl][k] * sW[k * HD + lane];

  float m = wsum(y) * (1.f / HD);
  float d = y - m;
  float v = wsum(d * d) * (1.f / HD);
  float ln = d * rsqrtf(v + EPSV) * ln_g[lane] + ln_b[lane];
  h_out[(size_t)n * HD + lane] = h_in[(size_t)n * HD + lane] + ln;
}

// ---------------- fc_final: LN(64) -> [64x64]+b -> ELU -> [64x32]+b ----------------
__global__ __launch_bounds__(512) void fc_final_k(
    const float* __restrict__ h, const float* __restrict__ ln2_g,
    const float* __restrict__ ln2_b, const float* __restrict__ w3,
    const float* __restrict__ b3, const float* __restrict__ w4,
    const float* __restrict__ b4, float* __restrict__ out) {
  __shared__ float sW3[HD * HD];     // 16 KB
  __shared__ float sW4[HD * NOUT];   // 8 KB
  __shared__ float sx[8][HD];
  __shared__ float sz[8][HD];
  int tid = threadIdx.x;
  for (int i = tid; i < HD * HD; i += 512) sW3[i] = w3[i];
  for (int i = tid; i < HD * NOUT; i += 512) sW4[i] = w4[i];
  int wl = tid >> 6, lane = tid & 63;
  int n = blockIdx.x * 8 + wl;

  float hv = h[(size_t)n * HD + lane];
  float m = wsum(hv) * (1.f / HD);
  float d = hv - m;
  float v = wsum(d * d) * (1.f / HD);
  sx[wl][lane] = d * rsqrtf(v + EPSV) * ln2_g[lane] + ln2_b[lane];
  __syncthreads();

  float y = b3[lane];
#pragma unroll 8
  for (int k = 0; k < HD; ++k) y += sx[wl][k] * sW3[k * HD + lane];
  y = (y > 0.f) ? y : expm1f(y);
  sz[wl][lane] = y;
  __syncthreads();

  if (lane < NOUT) {
    float o = b4[lane];
#pragma unroll 8
    for (int j = 0; j < HD; ++j) o += sz[wl][j] * sW4[j * NOUT + lane];
    out[(size_t)n * NOUT + lane] = o;
  }
}

extern "C" void kernel_launch(void* const* d_in, const int* in_sizes, int n_in,
                              void* d_out, int out_size, void* d_ws, size_t ws_size,
                              hipStream_t stream) {
  const float* x      = (const float*)d_in[0];
  const float* ew     = (const float*)d_in[1];
  const int*   src    = (const int*)d_in[2];
  const int*   dst    = (const int*)d_in[3];
  const float* ln1_g  = (const float*)d_in[4];
  const float* ln1_b  = (const float*)d_in[5];
  const float* w1     = (const float*)d_in[6];
  const float* b1     = (const float*)d_in[7];
  const float* ln_g   = (const float*)d_in[8];
  const float* ln_b   = (const float*)d_in[9];
  const float* conv_w = (const float*)d_in[10];
  const float* conv_b = (const float*)d_in[11];
  const float* ln2_g  = (const float*)d_in[12];
  const float* ln2_b  = (const float*)d_in[13];
  const float* w3     = (const float*)d_in[14];
  const float* b3     = (const float*)d_in[15];
  const float* w4     = (const float*)d_in[16];
  const float* b4     = (const float*)d_in[17];
  float* out = (float*)d_out;

  char* ws = (char*)d_ws;
  float* hA     = (float*)ws;                       // 16 MB
  float* hB     = hA + (size_t)NN * HD;             // 16 MB
  int*   rowptr = (int*)(hB + (size_t)NN * HD);     // N+1 (padded to N+64)
  int*   counts = rowptr + (NN + 64);               // N
  int*   cursor = counts + NN;                      // N
  int*   bsum   = cursor + NN;                      // 256
  int2*  edge   = (int2*)(bsum + 256);              // E * 8B

  hipMemsetAsync(counts, 0, NN * sizeof(int), stream);
  hist_k<<<NE / 256, 256, 0, stream>>>(dst, counts);
  scanA_k<<<NN / 256, 256, 0, stream>>>(counts, bsum);
  scanB_k<<<1, 256, 0, stream>>>(bsum);
  scanC_k<<<NN / 256, 256, 0, stream>>>(counts, bsum, rowptr, cursor);
  scatter_k<<<NE / 256, 256, 0, stream>>>(src, dst, ew, cursor, edge);

  fc_first_k<<<NN / 8, 512, 0, stream>>>(x, ln1_g, ln1_b, w1, b1, ln_g, ln_b, hA);
  conv_k<<<NN / 8, 512, 0, stream>>>(hA, hB, rowptr, edge,
                                     conv_w,        conv_b,       ln_g, ln_b);
  conv_k<<<NN / 8, 512, 0, stream>>>(hB, hA, rowptr, edge,
                                     conv_w + 4096, conv_b + 64,  ln_g, ln_b);
  conv_k<<<NN / 8, 512, 0, stream>>>(hA, hB, rowptr, edge,
                                     conv_w + 8192, conv_b + 128, ln_g, ln_b);
  fc_final_k<<<NN / 8, 512, 0, stream>>>(hB, ln2_g, ln2_b, w3, b3, w4, b4, out);
}

// Round 4
// 408.834 us; speedup vs baseline: 1.9447x; 1.1491x over previous
//
#include <hip/hip_runtime.h>

#define NN   65536
#define NE   1048576
#define FIN  128
#define HD   64
#define NOUT 32
#define EPSV 1e-5f

__device__ __forceinline__ float wsum(float v) {
#pragma unroll
  for (int o = 32; o > 0; o >>= 1) v += __shfl_xor(v, o, 64);
  return v;
}

// ---------------- CSR build (dst-sorted, packed edges) ----------------

__global__ void hist_k(const int* __restrict__ dst, int* counts) {
  int i = blockIdx.x * blockDim.x + threadIdx.x;
  atomicAdd(&counts[dst[i]], 1);
}

__global__ __launch_bounds__(256) void scanA_k(const int* __restrict__ counts,
                                               int* __restrict__ bsum) {
  __shared__ int ss[256];
  int t = threadIdx.x;
  ss[t] = counts[blockIdx.x * 256 + t];
  __syncthreads();
  for (int off = 128; off > 0; off >>= 1) {
    if (t < off) ss[t] += ss[t + off];
    __syncthreads();
  }
  if (t == 0) bsum[blockIdx.x] = ss[0];
}

__global__ __launch_bounds__(256) void scanB_k(int* __restrict__ bsum) {
  __shared__ int ss[256];
  int t = threadIdx.x;
  ss[t] = bsum[t];
  __syncthreads();
  for (int off = 1; off < 256; off <<= 1) {
    int v = (t >= off) ? ss[t - off] : 0;
    __syncthreads();
    ss[t] += v;
    __syncthreads();
  }
  bsum[t] = (t == 0) ? 0 : ss[t - 1];
}

__global__ __launch_bounds__(256) void scanC_k(const int* __restrict__ counts,
                                               const int* __restrict__ bsum,
                                               int* __restrict__ rowptr,
                                               int* __restrict__ cursor) {
  __shared__ int ss[256];
  int t = threadIdx.x;
  int g = blockIdx.x * 256 + t;
  int c = counts[g];
  ss[t] = c;
  __syncthreads();
  for (int off = 1; off < 256; off <<= 1) {
    int v = (t >= off) ? ss[t - off] : 0;
    __syncthreads();
    ss[t] += v;
    __syncthreads();
  }
  int excl = ss[t] - c + bsum[blockIdx.x];
  rowptr[g] = excl;
  cursor[g] = excl;
  if (g == NN - 1) rowptr[NN] = excl + c;
}

__global__ void scatter_k(const int* __restrict__ src, const int* __restrict__ dst,
                          const float* __restrict__ ew, int* cursor,
                          int2* __restrict__ edge) {
  int i = blockIdx.x * blockDim.x + threadIdx.x;
  int d = dst[i];
  int pos = atomicAdd(&cursor[d], 1);
  edge[pos] = make_int2(src[i], __float_as_int(ew[i]));
}

// ---------------- fc_first: LN(128) -> [128x64] -> ELU -> LN(64) ----------------
// lane = node. acc[64] in regs; W broadcast from LDS (uniform float4 reads).
__global__ __launch_bounds__(256) void fc_first_k(
    const float* __restrict__ x, const float* __restrict__ ln1_g,
    const float* __restrict__ ln1_b, const float* __restrict__ w1,
    const float* __restrict__ b1, const float* __restrict__ ln_g,
    const float* __restrict__ ln_b, float* __restrict__ hA) {
  __shared__ __align__(16) float sW[FIN * HD];   // 32 KB, [k][j]
  __shared__ __align__(16) float sG[FIN], sB[FIN];
  __shared__ __align__(16) float sB1[HD], sLG[HD], sLB[HD];
  int tid = threadIdx.x;
  {
    const float4* w4 = (const float4*)w1;
    float4* s4 = (float4*)sW;
    for (int i = tid; i < FIN * HD / 4; i += 256) s4[i] = w4[i];
    if (tid < FIN) { sG[tid] = ln1_g[tid]; sB[tid] = ln1_b[tid]; }
    if (tid < HD) { sB1[tid] = b1[tid]; sLG[tid] = ln_g[tid]; sLB[tid] = ln_b[tid]; }
  }
  __syncthreads();

  int node = blockIdx.x * 256 + tid;
  const float4* xp = (const float4*)(x + (size_t)node * FIN);

  float s = 0.f, s2 = 0.f;
  for (int i = 0; i < FIN / 4; ++i) {
    float4 v = xp[i];
    s += v.x + v.y + v.z + v.w;
    s2 += v.x * v.x + v.y * v.y + v.z * v.z + v.w * v.w;
  }
  float mean = s * (1.f / FIN);
  float var = s2 * (1.f / FIN) - mean * mean;
  float r = rsqrtf(var + EPSV);

  float acc[HD];
#pragma unroll
  for (int jb = 0; jb < HD / 4; ++jb) {
    float4 b = ((const float4*)sB1)[jb];
    acc[jb * 4 + 0] = b.x; acc[jb * 4 + 1] = b.y;
    acc[jb * 4 + 2] = b.z; acc[jb * 4 + 3] = b.w;
  }
  const float4* sW4 = (const float4*)sW;   // 16 float4 per k-row
  for (int k4 = 0; k4 < FIN / 4; ++k4) {
    float4 xk = xp[k4];                    // L1/L2 re-read
    float4 g4 = ((const float4*)sG)[k4];
    float4 bb4 = ((const float4*)sB)[k4];
    float xn0 = (xk.x - mean) * r * g4.x + bb4.x;
    float xn1 = (xk.y - mean) * r * g4.y + bb4.y;
    float xn2 = (xk.z - mean) * r * g4.z + bb4.z;
    float xn3 = (xk.w - mean) * r * g4.w + bb4.w;
#pragma unroll
    for (int jb = 0; jb < HD / 4; ++jb) {
      float4 w0 = sW4[(k4 * 4 + 0) * 16 + jb];
      float4 w1v = sW4[(k4 * 4 + 1) * 16 + jb];
      float4 w2 = sW4[(k4 * 4 + 2) * 16 + jb];
      float4 w3v = sW4[(k4 * 4 + 3) * 16 + jb];
      acc[jb * 4 + 0] += xn0 * w0.x + xn1 * w1v.x + xn2 * w2.x + xn3 * w3v.x;
      acc[jb * 4 + 1] += xn0 * w0.y + xn1 * w1v.y + xn2 * w2.y + xn3 * w3v.y;
      acc[jb * 4 + 2] += xn0 * w0.z + xn1 * w1v.z + xn2 * w2.z + xn3 * w3v.z;
      acc[jb * 4 + 3] += xn0 * w0.w + xn1 * w1v.w + xn2 * w2.w + xn3 * w3v.w;
    }
  }

  float s3 = 0.f;
#pragma unroll
  for (int j = 0; j < HD; ++j) {
    float y = acc[j];
    y = (y > 0.f) ? y : expm1f(y);
    acc[j] = y;
    s3 += y;
  }
  float m2 = s3 * (1.f / HD);
  float v2 = 0.f;
#pragma unroll
  for (int j = 0; j < HD; ++j) { float d = acc[j] - m2; v2 += d * d; }
  float r2 = rsqrtf(v2 * (1.f / HD) + EPSV);

  float4* hp = (float4*)(hA + (size_t)node * HD);
#pragma unroll
  for (int jb = 0; jb < HD / 4; ++jb) {
    float4 g4 = ((const float4*)sLG)[jb];
    float4 b4 = ((const float4*)sLB)[jb];
    float4 o;
    o.x = (acc[jb * 4 + 0] - m2) * r2 * g4.x + b4.x;
    o.y = (acc[jb * 4 + 1] - m2) * r2 * g4.y + b4.y;
    o.z = (acc[jb * 4 + 2] - m2) * r2 * g4.z + b4.z;
    o.w = (acc[jb * 4 + 3] - m2) * r2 * g4.w + b4.w;
    hp[jb] = o;
  }
}

// ---------------- conv layer: gather-agg -> [64x64]+b -> LN -> h += ----------------
__global__ __launch_bounds__(512) void conv_k(
    const float* __restrict__ h_in, float* __restrict__ h_out,
    const int* __restrict__ rowptr, const int2* __restrict__ edge,
    const float* __restrict__ W, const float* __restrict__ B,
    const float* __restrict__ ln_g, const float* __restrict__ ln_b) {
  __shared__ __align__(16) float sWt[HD * 68];   // [j][k], pad 68 -> conflict-free b128
  __shared__ __align__(16) float sagg[8][HD];
  int tid = threadIdx.x;
  for (int i = tid; i < HD * HD; i += 512) {
    int k = i >> 6, j = i & 63;
    sWt[j * 68 + k] = W[i];
  }
  int wl = tid >> 6, lane = tid & 63;
  int n = blockIdx.x * 8 + wl;

  int beg = rowptr[n], end = rowptr[n + 1];
  float acc = 0.f;
  int e = beg;
  for (; e + 8 <= end; e += 8) {
    int2 E[8];
#pragma unroll
    for (int j = 0; j < 8; ++j) E[j] = edge[e + j];
    float g[8];
#pragma unroll
    for (int j = 0; j < 8; ++j) g[j] = h_in[(size_t)E[j].x * HD + lane];
#pragma unroll
    for (int j = 0; j < 8; ++j) acc += g[j] * __int_as_float(E[j].y);
  }
  for (; e + 4 <= end; e += 4) {
    int2 E[4];
#pragma unroll
    for (int j = 0; j < 4; ++j) E[j] = edge[e + j];
    float g[4];
#pragma unroll
    for (int j = 0; j < 4; ++j) g[j] = h_in[(size_t)E[j].x * HD + lane];
#pragma unroll
    for (int j = 0; j < 4; ++j) acc += g[j] * __int_as_float(E[j].y);
  }
  for (; e < end; ++e) {
    int2 e0 = edge[e];
    acc += h_in[(size_t)e0.x * HD + lane] * __int_as_float(e0.y);
  }
  sagg[wl][lane] = acc;
  __syncthreads();

  float y = B[lane];
  const float4* ar = (const float4*)sagg[wl];
  const float4* wr = (const float4*)&sWt[lane * 68];
#pragma unroll
  for (int k4 = 0; k4 < HD / 4; ++k4) {
    float4 a4 = ar[k4];
    float4 w4v = wr[k4];
    y += a4.x * w4v.x + a4.y * w4v.y + a4.z * w4v.z + a4.w * w4v.w;
  }

  float m = wsum(y) * (1.f / HD);
  float d = y - m;
  float v = wsum(d * d) * (1.f / HD);
  float ln = d * rsqrtf(v + EPSV) * ln_g[lane] + ln_b[lane];
  h_out[(size_t)n * HD + lane] = h_in[(size_t)n * HD + lane] + ln;
}

// ---------------- fc_final: LN(64) -> [64x64]+b3 -> ELU -> [64x32]+b4 ----------------
__global__ __launch_bounds__(256) void fc_final_k(
    const float* __restrict__ h, const float* __restrict__ ln2_g,
    const float* __restrict__ ln2_b, const float* __restrict__ w3,
    const float* __restrict__ b3, const float* __restrict__ w4,
    const float* __restrict__ b4, float* __restrict__ out) {
  __shared__ __align__(16) float sW3[HD * HD];     // [k][j]
  __shared__ __align__(16) float sW4[HD * NOUT];   // [k][j]
  __shared__ __align__(16) float sG[HD], sB[HD], sB3[HD], sB4[NOUT];
  int tid = threadIdx.x;
  {
    const float4* a = (const float4*)w3;
    float4* d4 = (float4*)sW3;
    for (int i = tid; i < HD * HD / 4; i += 256) d4[i] = a[i];
    const float4* c = (const float4*)w4;
    float4* e4 = (float4*)sW4;
    for (int i = tid; i < HD * NOUT / 4; i += 256) e4[i] = c[i];
    if (tid < HD) { sG[tid] = ln2_g[tid]; sB[tid] = ln2_b[tid]; sB3[tid] = b3[tid]; }
    if (tid < NOUT) sB4[tid] = b4[tid];
  }
  __syncthreads();

  int node = blockIdx.x * 256 + tid;
  const float4* hp = (const float4*)(h + (size_t)node * HD);

  float s = 0.f, s2 = 0.f;
  for (int i = 0; i < HD / 4; ++i) {
    float4 v = hp[i];
    s += v.x + v.y + v.z + v.w;
    s2 += v.x * v.x + v.y * v.y + v.z * v.z + v.w * v.w;
  }
  float mean = s * (1.f / HD);
  float var = s2 * (1.f / HD) - mean * mean;
  float r = rsqrtf(var + EPSV);

  float acc[HD];
#pragma unroll
  for (int jb = 0; jb < HD / 4; ++jb) {
    float4 b = ((const float4*)sB3)[jb];
    acc[jb * 4 + 0] = b.x; acc[jb * 4 + 1] = b.y;
    acc[jb * 4 + 2] = b.z; acc[jb * 4 + 3] = b.w;
  }
  const float4* sW34 = (const float4*)sW3;
  for (int k4 = 0; k4 < HD / 4; ++k4) {
    float4 xk = hp[k4];
    float4 g4 = ((const float4*)sG)[k4];
    float4 bb4 = ((const float4*)sB)[k4];
    float xn0 = (xk.x - mean) * r * g4.x + bb4.x;
    float xn1 = (xk.y - mean) * r * g4.y + bb4.y;
    float xn2 = (xk.z - mean) * r * g4.z + bb4.z;
    float xn3 = (xk.w - mean) * r * g4.w + bb4.w;
#pragma unroll
    for (int jb = 0; jb < HD / 4; ++jb) {
      float4 w0 = sW34[(k4 * 4 + 0) * 16 + jb];
      float4 w1v = sW34[(k4 * 4 + 1) * 16 + jb];
      float4 w2 = sW34[(k4 * 4 + 2) * 16 + jb];
      float4 w3v = sW34[(k4 * 4 + 3) * 16 + jb];
      acc[jb * 4 + 0] += xn0 * w0.x + xn1 * w1v.x + xn2 * w2.x + xn3 * w3v.x;
      acc[jb * 4 + 1] += xn0 * w0.y + xn1 * w1v.y + xn2 * w2.y + xn3 * w3v.y;
      acc[jb * 4 + 2] += xn0 * w0.z + xn1 * w1v.z + xn2 * w2.z + xn3 * w3v.z;
      acc[jb * 4 + 3] += xn0 * w0.w + xn1 * w1v.w + xn2 * w2.w + xn3 * w3v.w;
    }
  }

#pragma unroll
  for (int j = 0; j < HD; ++j) {
    float y = acc[j];
    acc[j] = (y > 0.f) ? y : expm1f(y);
  }

  float outv[NOUT];
#pragma unroll
  for (int jb = 0; jb < NOUT / 4; ++jb) {
    float4 b = ((const float4*)sB4)[jb];
    outv[jb * 4 + 0] = b.x; outv[jb * 4 + 1] = b.y;
    outv[jb * 4 + 2] = b.z; outv[jb * 4 + 3] = b.w;
  }
  const float4* sW44 = (const float4*)sW4;
#pragma unroll
  for (int k = 0; k < HD; ++k) {
    float zk = acc[k];
#pragma unroll
    for (int jb = 0; jb < NOUT / 4; ++jb) {
      float4 w = sW44[k * 8 + jb];
      outv[jb * 4 + 0] += zk * w.x;
      outv[jb * 4 + 1] += zk * w.y;
      outv[jb * 4 + 2] += zk * w.z;
      outv[jb * 4 + 3] += zk * w.w;
    }
  }
  float4* op = (float4*)(out + (size_t)node * NOUT);
#pragma unroll
  for (int jb = 0; jb < NOUT / 4; ++jb) {
    float4 o;
    o.x = outv[jb * 4 + 0]; o.y = outv[jb * 4 + 1];
    o.z = outv[jb * 4 + 2]; o.w = outv[jb * 4 + 3];
    op[jb] = o;
  }
}

extern "C" void kernel_launch(void* const* d_in, const int* in_sizes, int n_in,
                              void* d_out, int out_size, void* d_ws, size_t ws_size,
                              hipStream_t stream) {
  const float* x      = (const float*)d_in[0];
  const float* ew     = (const float*)d_in[1];
  const int*   src    = (const int*)d_in[2];
  const int*   dst    = (const int*)d_in[3];
  const float* ln1_g  = (const float*)d_in[4];
  const float* ln1_b  = (const float*)d_in[5];
  const float* w1     = (const float*)d_in[6];
  const float* b1     = (const float*)d_in[7];
  const float* ln_g   = (const float*)d_in[8];
  const float* ln_b   = (const float*)d_in[9];
  const float* conv_w = (const float*)d_in[10];
  const float* conv_b = (const float*)d_in[11];
  const float* ln2_g  = (const float*)d_in[12];
  const float* ln2_b  = (const float*)d_in[13];
  const float* w3     = (const float*)d_in[14];
  const float* b3     = (const float*)d_in[15];
  const float* w4     = (const float*)d_in[16];
  const float* b4     = (const float*)d_in[17];
  float* out = (float*)d_out;

  char* ws = (char*)d_ws;
  float* hA     = (float*)ws;                       // 16 MB
  float* hB     = hA + (size_t)NN * HD;             // 16 MB
  int*   rowptr = (int*)(hB + (size_t)NN * HD);     // N+1 (padded to N+64)
  int*   counts = rowptr + (NN + 64);               // N
  int*   cursor = counts + NN;                      // N
  int*   bsum   = cursor + NN;                      // 256
  int2*  edge   = (int2*)(bsum + 256);              // E * 8B

  hipMemsetAsync(counts, 0, NN * sizeof(int), stream);
  hist_k<<<NE / 256, 256, 0, stream>>>(dst, counts);
  scanA_k<<<NN / 256, 256, 0, stream>>>(counts, bsum);
  scanB_k<<<1, 256, 0, stream>>>(bsum);
  scanC_k<<<NN / 256, 256, 0, stream>>>(counts, bsum, rowptr, cursor);
  scatter_k<<<NE / 256, 256, 0, stream>>>(src, dst, ew, cursor, edge);

  fc_first_k<<<NN / 256, 256, 0, stream>>>(x, ln1_g, ln1_b, w1, b1, ln_g, ln_b, hA);
  conv_k<<<NN / 8, 512, 0, stream>>>(hA, hB, rowptr, edge,
                                     conv_w,        conv_b,       ln_g, ln_b);
  conv_k<<<NN / 8, 512, 0, stream>>>(hB, hA, rowptr, edge,
                                     conv_w + 4096, conv_b + 64,  ln_g, ln_b);
  conv_k<<<NN / 8, 512, 0, stream>>>(hA, hB, rowptr, edge,
                                     conv_w + 8192, conv_b + 128, ln_g, ln_b);
  fc_final_k<<<NN / 256, 256, 0, stream>>>(hB, ln2_g, ln2_b, w3, b3, w4, b4, out);
}